// Round 9
// baseline (240.545 us; speedup 1.0000x reference)
//
#include <hip/hip_runtime.h>
#include <hip/hip_bf16.h>

#define HW 2304          // 48*48
#define NB 8             // batch
#define NC 256           // input channels
#define HID 128          // heads*dim_head
#define DH 32            // dim_head
#define NH 4             // heads
#define SCALE 0.17677669529663687f   // 1/sqrt(32)
#define LOG2E 1.4426950408889634f
#define LN2   0.6931471805599453f

using bf16x8 = __attribute__((ext_vector_type(8))) short;
using f32x4  = __attribute__((ext_vector_type(4))) float;

__device__ __forceinline__ short f2bf(float f) {   // RNE float->bf16
    unsigned u = __float_as_uint(f);
    u += 0x7FFF + ((u >> 16) & 1);
    return (short)(u >> 16);
}
__device__ __forceinline__ unsigned pk2bf(float a, float b) {  // pack 2 bf16 (RNE)
    union { __hip_bfloat162 h; unsigned u; } cv;
    cv.h = __float22bfloat162_rn(float2{a, b});
    return cv.u;
}
__device__ __forceinline__ void gld16(const void* g, void* l) {  // 16B global->LDS DMA
    __builtin_amdgcn_global_load_lds(
        (const __attribute__((address_space(1))) unsigned*)g,
        (__attribute__((address_space(3))) unsigned*)l, 16, 0, 0);
}

// ---------------------------------------------------------------------------
// Fused pre-pass. z<8: x [b][256][2304] fp32 -> Xt [b][2304][256] bf16.
// z==8: weight fp32->bf16 conversion + zero the E/ticket words.
// ---------------------------------------------------------------------------
__global__ __launch_bounds__(256)
void prep(const float* __restrict__ x, const float* __restrict__ wq,
          const float* __restrict__ wo, short* __restrict__ Xt,
          short* __restrict__ Wq, short* __restrict__ Wo, float* __restrict__ wsz)
{
    if (blockIdx.z == 8) {
        const int bid = blockIdx.x + 72 * blockIdx.y;
        if (bid == 0 && threadIdx.x == 0) { wsz[0] = 0.f; ((int*)wsz)[1] = 0; }
        const int i = bid * 256 + threadIdx.x;
        if (i < 384 * 256) Wq[i] = f2bf(wq[i]);
        if (i < 256 * 128) Wo[i] = f2bf(wo[i]);
        return;
    }
    __shared__ float T[32][33];
    const int b = blockIdx.z, c0 = blockIdx.y * 32, s0 = blockIdx.x * 32;
    const int ts = threadIdx.x & 31, tc = threadIdx.x >> 5;
    #pragma unroll
    for (int cc = tc; cc < 32; cc += 8)
        T[cc][ts] = x[((size_t)b * NC + c0 + cc) * HW + s0 + ts];
    __syncthreads();
    const int tcc = threadIdx.x & 31, tss = threadIdx.x >> 5;
    #pragma unroll
    for (int ss = tss; ss < 32; ss += 8)
        Xt[((size_t)b * HW + s0 + ss) * NC + c0 + tcc] = f2bf(T[tcc][ss]);
}

// ---------------------------------------------------------------------------
// LDS-free MFMA 1x1-conv GEMM (unchanged).
// Q pre-scaled by SCALE*LOG2E; K pair-permuted in 32-key groups; V [bh][dh][s].
// ---------------------------------------------------------------------------
template<int KD, bool QKV>
__global__ __launch_bounds__(256, 4)
void conv_mfma(const short* __restrict__ A, const short* __restrict__ Bt,
               const float* __restrict__ bias, float* __restrict__ out0,
               short* __restrict__ Qb, short* __restrict__ Kb,
               short* __restrict__ Vb, float* __restrict__ E,
               int* __restrict__ ticket, int nblocks, float* __restrict__ edst)
{
    const int b  = blockIdx.z;
    const int bm = blockIdx.y * 64;
    const int bn = blockIdx.x * 128;
    const int t  = threadIdx.x;
    const int w  = t >> 6, lane = t & 63;
    const int n16 = lane & 15, quad = lane >> 4;

    __shared__ float red[4];

    const short* Ag  = A + (size_t)(bm + n16) * KD + quad * 8;
    const short* Bg0 = Bt + ((size_t)b * HW + bn + (w * 2 + 0) * 16 + n16) * KD + quad * 8;
    const short* Bg1 = Bt + ((size_t)b * HW + bn + (w * 2 + 1) * 16 + n16) * KD + quad * 8;

    f32x4 acc[4][2] = {};

    for (int kc = 0; kc < KD; kc += 32) {
        bf16x8 am[4], bq[2];
        #pragma unroll
        for (int tm = 0; tm < 4; ++tm)
            am[tm] = *(const bf16x8*)(Ag + (size_t)tm * 16 * KD + kc);
        bq[0] = *(const bf16x8*)(Bg0 + kc);
        bq[1] = *(const bf16x8*)(Bg1 + kc);
        #pragma unroll
        for (int tm = 0; tm < 4; ++tm)
            #pragma unroll
            for (int j = 0; j < 2; ++j)
                acc[tm][j] = __builtin_amdgcn_mfma_f32_16x16x32_bf16(am[tm], bq[j], acc[tm][j], 0, 0, 0);
    }

    float e = 0.f;
    #pragma unroll
    for (int tm = 0; tm < 4; ++tm) {
        const int o0 = bm + tm * 16 + quad * 4;
        const float4 bb = *(const float4*)(bias + o0);
        #pragma unroll
        for (int j = 0; j < 2; ++j) {
            const int s = bn + (w * 2 + j) * 16 + n16;
            float v[4] = {acc[tm][j][0] + bb.x, acc[tm][j][1] + bb.y,
                          acc[tm][j][2] + bb.z, acc[tm][j][3] + bb.w};
            e -= 0.5f * (v[0]*v[0] + v[1]*v[1] + v[2]*v[2] + v[3]*v[3]);
            if (QKV) {
                if (o0 < HID) {                       // Q: scaled by SCALE*log2e
                    const int h = o0 >> 5, dh0 = o0 & 31;
                    const float qs = SCALE * LOG2E;
                    short4 pk = {f2bf(v[0]*qs), f2bf(v[1]*qs),
                                 f2bf(v[2]*qs), f2bf(v[3]*qs)};
                    *(short4*)(Qb + ((size_t)(b * NH + h) * HW + s) * DH + dh0) = pk;
                } else if (o0 < 2 * HID) {            // K: pair-permuted rows
                    const int c = o0 - HID, h = c >> 5, dh0 = c & 31;
                    const int g = s & 31;
                    const int sp = (s & ~31) | ((g & 1) << 4) | (g >> 1);
                    short4 pk = {f2bf(v[0]), f2bf(v[1]), f2bf(v[2]), f2bf(v[3])};
                    *(short4*)(Kb + ((size_t)(b * NH + h) * HW + sp) * DH + dh0) = pk;
                } else {                              // V: [bh][dh][s]
                    const int c = o0 - 2 * HID, h = c >> 5, dh0 = c & 31;
                    #pragma unroll
                    for (int r = 0; r < 4; ++r)
                        Vb[((size_t)(b * NH + h) * DH + dh0 + r) * HW + s] = f2bf(v[r]);
                }
            } else {
                #pragma unroll
                for (int r = 0; r < 4; ++r)
                    out0[((size_t)b * NC + o0 + r) * HW + s] = v[r];
            }
        }
    }

    #pragma unroll
    for (int off = 32; off > 0; off >>= 1) e += __shfl_down(e, off);
    if (lane == 0) red[w] = e;
    __syncthreads();
    if (t == 0) {
        atomicAdd(E, red[0] + red[1] + red[2] + red[3]);
        if (!QKV) {
            __threadfence();
            const int prev = atomicAdd(ticket, 1);
            if (prev == nblocks - 1) {
                __threadfence();
                edst[0] = atomicAdd(E, 0.f);
            }
        }
    }
}

// ---------------------------------------------------------------------------
// Flash attention v6. Block = 64 queries x 4 waves; wave w owns 16 queries
// and walks ALL 2304 keys, 36 iterations x 64 keys (2 chunks of 32). Grid
// (36, 32) = 1152 blocks = 4.5/CU (2x round 8 — flash was grid-limited).
// Per iteration: shared 8KB pair of K/V chunks DMA'd by all 256 threads
// (2 gld16 each, XOR-swizzled), double-buffered; ONE barrier per 64 keys
// (its vmcnt(0) drain = DMA completion wait). Per-wave P tiles, separate
// buffer per chunk (no intra-iteration WAR). m=0 fixed shift, raw v_exp.
// ---------------------------------------------------------------------------
__global__ __launch_bounds__(256)
void flash6(const short* __restrict__ Qb, const short* __restrict__ Kb,
            const short* __restrict__ Vb, short* __restrict__ attT,
            float* __restrict__ E)
{
    __shared__ __align__(16) char smem[16384 + 4 * 2560];
    // [0,16384): KV pair buffers: parity p at p*8192; chunk ca at +ca*4096
    //            (each 4KB: K keys0-15 1KB | keys16-31 1KB | V dh0-15 | dh16-31)
    // [16384,+): per-wave P: wave w at 16384 + w*2560; chunk ca at +ca*1280
    //            (16 rows x 40 shorts)

    const int bh   = blockIdx.y;
    const int w    = threadIdx.x >> 6;
    const int lane = threadIdx.x & 63;
    const int n16  = lane & 15, quad = lane >> 4;
    const int qb   = blockIdx.x * 64 + w * 16;

    const bf16x8 aq = *(const bf16x8*)(Qb + ((size_t)bh * HW + qb + n16) * DH + quad * 8);

    // DMA role: waves 0,1 -> K halves; waves 2,3 -> V halves; lane L fetches
    // global 16B block (row rL, chunk cL^(rL&3)) -> HW deposits at base+L*16.
    const int rL = lane >> 2, cL = (lane & 3) ^ (rL & 3);
    const char* gbase; size_t gstep;
    if (w < 2) {
        gbase = (const char*)(Kb + (size_t)bh * HW * DH) + ((w & 1) * 16 + rL) * 64 + cL * 16;
        gstep = 2048;                      // 32 keys * 64 B
    } else {
        gbase = (const char*)(Vb + (size_t)bh * DH * HW)
              + (size_t)((w & 1) * 16 + rL) * (HW * 2) + cL * 16;
        gstep = 64;                        // 32 keys * 2 B per dh-row
    }

    // preload pair 0 (chunks 0,1) -> parity 0
    gld16(gbase,         smem + 0    + w * 1024);
    gld16(gbase + gstep, smem + 4096 + w * 1024);

    f32x4 acc0 = {}, acc1 = {};
    float ls[4] = {}, ts[4] = {};
    const int swz = (quad ^ (n16 & 3)) * 8;   // frag-read XOR swizzle (shorts)

    char* Pbase = smem + 16384 + w * 2560;

    for (int it = 0; it < 36; ++it) {
        const int p = it & 1;
        __syncthreads();                   // pair `it` landed; pair it-1 fully read
        if (it + 1 < 36) {
            const size_t g0 = (size_t)(2 * it + 2) * gstep;
            gld16(gbase + g0,         smem + (p ^ 1) * 8192 + 0    + w * 1024);
            gld16(gbase + g0 + gstep, smem + (p ^ 1) * 8192 + 4096 + w * 1024);
        }

        #pragma unroll
        for (int ca = 0; ca < 2; ++ca) {
            const short* kb = (const short*)(smem + p * 8192 + ca * 4096);
            short* Ps = (short*)(Pbase + ca * 1280);
            unsigned* P32 = (unsigned*)Ps;

            const bf16x8 bk0 = *(const bf16x8*)(kb + n16 * 32 + swz);          // keys(perm) 0-15
            const bf16x8 bk1 = *(const bf16x8*)(kb + 512  + n16 * 32 + swz);   // keys(perm) 16-31
            const bf16x8 bv0 = *(const bf16x8*)(kb + 1024 + n16 * 32 + swz);   // dh 0-15
            const bf16x8 bv1 = *(const bf16x8*)(kb + 1536 + n16 * 32 + swz);   // dh 16-31

            f32x4 z = {};
            const f32x4 s0 = __builtin_amdgcn_mfma_f32_16x16x32_bf16(aq, bk0, z, 0, 0, 0);
            const f32x4 s1 = __builtin_amdgcn_mfma_f32_16x16x32_bf16(aq, bk1, z, 0, 0, 0);
            #pragma unroll
            for (int r = 0; r < 4; ++r) {
                const float p0 = __builtin_amdgcn_exp2f(s0[r]);   // key 2*n16
                const float p1 = __builtin_amdgcn_exp2f(s1[r]);   // key 2*n16+1
                ls[r] += p0 + p1;
                ts[r] += p0 * s0[r] + p1 * s1[r];
                P32[(quad * 4 + r) * 20 + n16] = pk2bf(p0, p1);
            }
            const bf16x8 pa = *(const bf16x8*)(Ps + n16 * 40 + quad * 8);
            acc0 = __builtin_amdgcn_mfma_f32_16x16x32_bf16(pa, bv0, acc0, 0, 0, 0);
            acc1 = __builtin_amdgcn_mfma_f32_16x16x32_bf16(pa, bv1, acc1, 0, 0, 0);
        }
    }

    // reduce ls/ts across the 16 lanes (key dim) of each quad group
    #pragma unroll
    for (int m = 1; m < 16; m <<= 1)
        #pragma unroll
        for (int r = 0; r < 4; ++r) {
            ls[r] += __shfl_xor(ls[r], m);
            ts[r] += __shfl_xor(ts[r], m);
        }

    const int bb = bh >> 2, h = bh & 3;
    float e = 0.f;
    #pragma unroll
    for (int r = 0; r < 4; ++r) {
        const int q = qb + quad * 4 + r;
        const float L = ls[r];
        const float invl = 1.f / L;
        short* ap = attT + ((size_t)bb * HW + q) * HID + h * 32;
        ap[n16]      = f2bf(acc0[r] * invl);
        ap[n16 + 16] = f2bf(acc1[r] * invl);
        e += (LN2 * ts[r]) * invl - __logf(L);
    }
    e = (n16 == 0) ? e : 0.f;
    e += __shfl_xor(e, 16);
    e += __shfl_xor(e, 32);
    if (lane == 0) atomicAdd(E, e);
}

// ---------------------------------------------------------------------------
extern "C" void kernel_launch(void* const* d_in, const int* in_sizes, int n_in,
                              void* d_out, int out_size, void* d_ws, size_t ws_size,
                              hipStream_t stream) {
    const float* x     = (const float*)d_in[0];
    const float* w_qkv = (const float*)d_in[1];
    const float* b_qkv = (const float*)d_in[2];
    const float* w_out = (const float*)d_in[3];
    const float* b_out = (const float*)d_in[4];
    float* out = (float*)d_out;

    float* wsf    = (float*)d_ws;
    float* E      = wsf;                               // [0] energy accumulator
    int*   ticket = (int*)d_ws + 1;                    // [1] conv2 ticket
    short* Xt   = (short*)(wsf + 16);                  // bf16 [b][s][c]
    short* Wq   = Xt + (size_t)NB * HW * NC;           // bf16 [384][256]
    short* Wo   = Wq + 384 * 256;                      // bf16 [256][128]
    short* Qb   = Wo + 256 * 128;                      // bf16 [bh][s][dh] (xSCALE*log2e)
    short* Kb   = Qb + (size_t)NB * NH * HW * DH;      // bf16 [bh][s'][dh], pair-permuted
    short* Vb   = Kb + (size_t)NB * NH * HW * DH;      // bf16 [bh][dh][s]
    short* attT = Vb + (size_t)NB * NH * HW * DH;      // bf16 [b][s][hid]

    prep<<<dim3(HW / 32, NC / 32, NB + 1), 256, 0, stream>>>(
        x, w_qkv, w_out, Xt, Wq, Wo, wsf);
    conv_mfma<NC, true><<<dim3(18, 6, NB), 256, 0, stream>>>(
        Wq, Xt, b_qkv, nullptr, Qb, Kb, Vb, E, nullptr, 0, nullptr);
    flash6<<<dim3(HW / 64, NB * NH), 256, 0, stream>>>(
        Qb, Kb, Vb, attT, E);
    conv_mfma<HID, false><<<dim3(18, 4, NB), 256, 0, stream>>>(
        Wo, attT, b_out, out, nullptr, nullptr, nullptr, E,
        ticket, 18 * 4 * NB, out + (size_t)NB * NC * HW);
}

// Round 10
// 210.358 us; speedup vs baseline: 1.1435x; 1.1435x over previous
//
#include <hip/hip_runtime.h>
#include <hip/hip_bf16.h>

#define HW 2304          // 48*48
#define NB 8             // batch
#define NC 256           // input channels
#define HID 128          // heads*dim_head
#define DH 32            // dim_head
#define NH 4             // heads
#define SCALE 0.17677669529663687f   // 1/sqrt(32)
#define LOG2E 1.4426950408889634f
#define LN2   0.6931471805599453f

using bf16x8 = __attribute__((ext_vector_type(8))) short;
using f32x4  = __attribute__((ext_vector_type(4))) float;

__device__ __forceinline__ short f2bf(float f) {   // RNE float->bf16
    unsigned u = __float_as_uint(f);
    u += 0x7FFF + ((u >> 16) & 1);
    return (short)(u >> 16);
}
__device__ __forceinline__ unsigned pk2bf(float a, float b) {  // pack 2 bf16 (RNE)
    union { __hip_bfloat162 h; unsigned u; } cv;
    cv.h = __float22bfloat162_rn(float2{a, b});
    return cv.u;
}
__device__ __forceinline__ void gld16(const void* g, void* l) {  // 16B global->LDS DMA
    __builtin_amdgcn_global_load_lds(
        (const __attribute__((address_space(1))) unsigned*)g,
        (__attribute__((address_space(3))) unsigned*)l, 16, 0, 0);
}

// ---------------------------------------------------------------------------
// Fused pre-pass. z<8: x [b][256][2304] fp32 -> Xt [b][2304][256] bf16.
// z==8: weight fp32->bf16 conversion + zero the E/ticket words.
// ---------------------------------------------------------------------------
__global__ __launch_bounds__(256)
void prep(const float* __restrict__ x, const float* __restrict__ wq,
          const float* __restrict__ wo, short* __restrict__ Xt,
          short* __restrict__ Wq, short* __restrict__ Wo, float* __restrict__ wsz)
{
    if (blockIdx.z == 8) {
        const int bid = blockIdx.x + 72 * blockIdx.y;
        if (bid == 0 && threadIdx.x == 0) { wsz[0] = 0.f; ((int*)wsz)[1] = 0; }
        const int i = bid * 256 + threadIdx.x;
        if (i < 384 * 256) Wq[i] = f2bf(wq[i]);
        if (i < 256 * 128) Wo[i] = f2bf(wo[i]);
        return;
    }
    __shared__ float T[32][33];
    const int b = blockIdx.z, c0 = blockIdx.y * 32, s0 = blockIdx.x * 32;
    const int ts = threadIdx.x & 31, tc = threadIdx.x >> 5;
    #pragma unroll
    for (int cc = tc; cc < 32; cc += 8)
        T[cc][ts] = x[((size_t)b * NC + c0 + cc) * HW + s0 + ts];
    __syncthreads();
    const int tcc = threadIdx.x & 31, tss = threadIdx.x >> 5;
    #pragma unroll
    for (int ss = tss; ss < 32; ss += 8)
        Xt[((size_t)b * HW + s0 + ss) * NC + c0 + tcc] = f2bf(T[tcc][ss]);
}

// ---------------------------------------------------------------------------
// MFMA 1x1-conv GEMM with gld16-staged, double-buffered LDS tiles (m97-style:
// one barrier per 32-K chunk = DMA drain; MFMA stream never waits on VMEM).
// Tile M64 x N128. LDS per buffer: A 64x32 (4KB, 4 deposit ops) + B 128x32
// (8KB, 8 ops); 12 ops spread 3-per-wave. Deposit lane L holds global column
// block (L&3)^(rL&3) (XOR swizzle); frag read offset (quad^(n16&3))*16.
// Epilogue (unchanged): Q(xSCALE*LOG2E)/K(pair-permuted) [bh][s][dh],
// V [bh][dh][s]; else fp32 out + ticketed energy store.
// ---------------------------------------------------------------------------
template<int KD, bool QKV>
__global__ __launch_bounds__(256, 4)
void conv_mfma(const short* __restrict__ A, const short* __restrict__ Bt,
               const float* __restrict__ bias, float* __restrict__ out0,
               short* __restrict__ Qb, short* __restrict__ Kb,
               short* __restrict__ Vb, float* __restrict__ E,
               int* __restrict__ ticket, int nblocks, float* __restrict__ edst)
{
    const int b  = blockIdx.z;
    const int bm = blockIdx.y * 64;
    const int bn = blockIdx.x * 128;
    const int t  = threadIdx.x;
    const int w  = t >> 6, lane = t & 63;
    const int n16 = lane & 15, quad = lane >> 4;

    __shared__ __align__(16) char csm[24576];   // 2 x (A 4KB | B 8KB)
    __shared__ float red[4];

    // deposit-side global lane addresses
    const int rL = lane >> 2, cswz = (lane & 3) ^ (rL & 3);
    const char* agl = (const char*)(A  + (size_t)(bm + rL) * KD + cswz * 8);
    const char* bgl = (const char*)(Bt + ((size_t)b * HW + bn + rL) * KD + cswz * 8);

    auto issue = [&](int kc, int pbuf) {
        char* base = csm + pbuf * 12288;
        if (w == 0) {
            gld16(agl + (size_t)(0 * 16 * KD + kc) * 2, base + 0 * 1024);
            gld16(agl + (size_t)(1 * 16 * KD + kc) * 2, base + 1 * 1024);
            gld16(bgl + (size_t)(0 * 16 * KD + kc) * 2, base + 4096 + 0 * 1024);
        } else if (w == 1) {
            gld16(agl + (size_t)(2 * 16 * KD + kc) * 2, base + 2 * 1024);
            gld16(agl + (size_t)(3 * 16 * KD + kc) * 2, base + 3 * 1024);
            gld16(bgl + (size_t)(1 * 16 * KD + kc) * 2, base + 4096 + 1 * 1024);
        } else if (w == 2) {
            gld16(bgl + (size_t)(2 * 16 * KD + kc) * 2, base + 4096 + 2 * 1024);
            gld16(bgl + (size_t)(3 * 16 * KD + kc) * 2, base + 4096 + 3 * 1024);
            gld16(bgl + (size_t)(4 * 16 * KD + kc) * 2, base + 4096 + 4 * 1024);
        } else {
            gld16(bgl + (size_t)(5 * 16 * KD + kc) * 2, base + 4096 + 5 * 1024);
            gld16(bgl + (size_t)(6 * 16 * KD + kc) * 2, base + 4096 + 6 * 1024);
            gld16(bgl + (size_t)(7 * 16 * KD + kc) * 2, base + 4096 + 7 * 1024);
        }
    };

    f32x4 acc[4][2] = {};
    const int rsw = (quad ^ (n16 & 3)) * 16;    // frag-read swizzle (bytes)
    constexpr int NI = KD / 32;

    issue(0, 0);
    for (int ki = 0; ki < NI; ++ki) {
        const int p = ki & 1;
        __syncthreads();                        // vmcnt(0) drain: chunk ki landed
        if (ki + 1 < NI) issue((ki + 1) * 32, p ^ 1);

        const char* Ap = csm + p * 12288;
        const char* Bp = Ap + 4096;
        bf16x8 am[4], bq[2];
        #pragma unroll
        for (int tm = 0; tm < 4; ++tm)
            am[tm] = *(const bf16x8*)(Ap + tm * 1024 + n16 * 64 + rsw);
        #pragma unroll
        for (int j = 0; j < 2; ++j)
            bq[j] = *(const bf16x8*)(Bp + (w * 2 + j) * 1024 + n16 * 64 + rsw);
        #pragma unroll
        for (int tm = 0; tm < 4; ++tm)
            #pragma unroll
            for (int j = 0; j < 2; ++j)
                acc[tm][j] = __builtin_amdgcn_mfma_f32_16x16x32_bf16(am[tm], bq[j], acc[tm][j], 0, 0, 0);
    }

    float e = 0.f;
    #pragma unroll
    for (int tm = 0; tm < 4; ++tm) {
        const int o0 = bm + tm * 16 + quad * 4;
        const float4 bb = *(const float4*)(bias + o0);
        #pragma unroll
        for (int j = 0; j < 2; ++j) {
            const int s = bn + (w * 2 + j) * 16 + n16;
            float v[4] = {acc[tm][j][0] + bb.x, acc[tm][j][1] + bb.y,
                          acc[tm][j][2] + bb.z, acc[tm][j][3] + bb.w};
            e -= 0.5f * (v[0]*v[0] + v[1]*v[1] + v[2]*v[2] + v[3]*v[3]);
            if (QKV) {
                if (o0 < HID) {                       // Q: scaled by SCALE*log2e
                    const int h = o0 >> 5, dh0 = o0 & 31;
                    const float qs = SCALE * LOG2E;
                    short4 pk = {f2bf(v[0]*qs), f2bf(v[1]*qs),
                                 f2bf(v[2]*qs), f2bf(v[3]*qs)};
                    *(short4*)(Qb + ((size_t)(b * NH + h) * HW + s) * DH + dh0) = pk;
                } else if (o0 < 2 * HID) {            // K: pair-permuted rows
                    const int c = o0 - HID, h = c >> 5, dh0 = c & 31;
                    const int g = s & 31;
                    const int sp = (s & ~31) | ((g & 1) << 4) | (g >> 1);
                    short4 pk = {f2bf(v[0]), f2bf(v[1]), f2bf(v[2]), f2bf(v[3])};
                    *(short4*)(Kb + ((size_t)(b * NH + h) * HW + sp) * DH + dh0) = pk;
                } else {                              // V: [bh][dh][s]
                    const int c = o0 - 2 * HID, h = c >> 5, dh0 = c & 31;
                    #pragma unroll
                    for (int r = 0; r < 4; ++r)
                        Vb[((size_t)(b * NH + h) * DH + dh0 + r) * HW + s] = f2bf(v[r]);
                }
            } else {
                #pragma unroll
                for (int r = 0; r < 4; ++r)
                    out0[((size_t)b * NC + o0 + r) * HW + s] = v[r];
            }
        }
    }

    #pragma unroll
    for (int off = 32; off > 0; off >>= 1) e += __shfl_down(e, off);
    if (lane == 0) red[w] = e;
    __syncthreads();
    if (t == 0) {
        atomicAdd(E, red[0] + red[1] + red[2] + red[3]);
        if (!QKV) {
            __threadfence();
            const int prev = atomicAdd(ticket, 1);
            if (prev == nblocks - 1) {
                __threadfence();
                edst[0] = atomicAdd(E, 0.f);
            }
        }
    }
}

// ---------------------------------------------------------------------------
// Flash attention v7 = round-8 flash5 (best: 86us) with 64 keys per barrier.
// Block = 128 queries x 4 waves; wave owns 32 queries (2 qg), walks all 2304
// keys in 36 iterations x 64 keys (2 chunks of 32). Shared K/V pair buffers
// (2 x 8KB, double-buffered), DMA'd by all 256 threads (2 gld16 each, XOR
// swizzle); ONE barrier per 64 keys. m=0 fixed shift, raw v_exp_f32.
// Per-wave P tiles, separate buffer per chunk. attT out: bf16 [b][s][hid].
// ---------------------------------------------------------------------------
__global__ __launch_bounds__(256)
void flash7(const short* __restrict__ Qb, const short* __restrict__ Kb,
            const short* __restrict__ Vb, short* __restrict__ attT,
            float* __restrict__ E)
{
    __shared__ __align__(16) char smem[16384 + 4 * 5120];
    // [0,16384): KV buffers: parity p at p*8192, chunk ca at +ca*4096
    //            (4KB: K keys0-15 | keys16-31 | V dh0-15 | dh16-31, 1KB each)
    // [16384,+): per-wave P: wave w at +w*5120, chunk ca at +ca*2560
    //            (32 rows x 40 shorts)

    const int bh   = blockIdx.y;
    const int w    = threadIdx.x >> 6;
    const int lane = threadIdx.x & 63;
    const int n16  = lane & 15, quad = lane >> 4;
    const int qb   = blockIdx.x * 128 + w * 32;

    bf16x8 aq[2];
    #pragma unroll
    for (int qg = 0; qg < 2; ++qg)
        aq[qg] = *(const bf16x8*)(Qb + ((size_t)bh * HW + qb + qg * 16 + n16) * DH + quad * 8);

    // DMA role: waves 0,1 -> K halves; waves 2,3 -> V halves.
    const int rL = lane >> 2, cL = (lane & 3) ^ (rL & 3);
    const char* gbase; size_t gstep;
    if (w < 2) {
        gbase = (const char*)(Kb + (size_t)bh * HW * DH) + ((w & 1) * 16 + rL) * 64 + cL * 16;
        gstep = 2048;                      // 32 keys * 64 B
    } else {
        gbase = (const char*)(Vb + (size_t)bh * DH * HW)
              + (size_t)((w & 1) * 16 + rL) * (HW * 2) + cL * 16;
        gstep = 64;                        // 32 keys * 2 B per dh-row
    }

    // preload iteration 0 (chunks 0,1) -> parity 0
    gld16(gbase,         smem + 0    + w * 1024);
    gld16(gbase + gstep, smem + 4096 + w * 1024);

    f32x4 acc[2][2] = {};
    float ls[2][4] = {}, ts[2][4] = {};
    const int swz = (quad ^ (n16 & 3)) * 8;   // frag-read XOR swizzle (shorts)
    short* Pbase = (short*)(smem + 16384) + w * 2560;

    for (int it = 0; it < 36; ++it) {
        const int p = it & 1;
        __syncthreads();                   // pair `it` landed; pair it-1 fully read
        if (it + 1 < 36) {
            const size_t g0 = (size_t)(2 * it + 2) * gstep;
            gld16(gbase + g0,         smem + (p ^ 1) * 8192 + 0    + w * 1024);
            gld16(gbase + g0 + gstep, smem + (p ^ 1) * 8192 + 4096 + w * 1024);
        }

        #pragma unroll
        for (int ca = 0; ca < 2; ++ca) {
            const short* kb = (const short*)(smem + p * 8192 + ca * 4096);
            short* Ps = Pbase + ca * 1280;
            unsigned* P32 = (unsigned*)Ps;

            const bf16x8 bk0 = *(const bf16x8*)(kb + n16 * 32 + swz);          // keys(perm) 0-15
            const bf16x8 bk1 = *(const bf16x8*)(kb + 512  + n16 * 32 + swz);   // keys(perm) 16-31
            const bf16x8 bv0 = *(const bf16x8*)(kb + 1024 + n16 * 32 + swz);   // dh 0-15
            const bf16x8 bv1 = *(const bf16x8*)(kb + 1536 + n16 * 32 + swz);   // dh 16-31

            #pragma unroll
            for (int qg = 0; qg < 2; ++qg) {
                f32x4 z = {};
                const f32x4 s0 = __builtin_amdgcn_mfma_f32_16x16x32_bf16(aq[qg], bk0, z, 0, 0, 0);
                const f32x4 s1 = __builtin_amdgcn_mfma_f32_16x16x32_bf16(aq[qg], bk1, z, 0, 0, 0);
                #pragma unroll
                for (int r = 0; r < 4; ++r) {
                    const float p0 = __builtin_amdgcn_exp2f(s0[r]);   // key 2*n16
                    const float p1 = __builtin_amdgcn_exp2f(s1[r]);   // key 2*n16+1
                    ls[qg][r] += p0 + p1;
                    ts[qg][r] += p0 * s0[r] + p1 * s1[r];
                    P32[(qg * 16 + quad * 4 + r) * 20 + n16] = pk2bf(p0, p1);
                }
            }
            #pragma unroll
            for (int qg = 0; qg < 2; ++qg) {
                const bf16x8 pa = *(const bf16x8*)(Ps + (qg * 16 + n16) * 40 + quad * 8);
                acc[qg][0] = __builtin_amdgcn_mfma_f32_16x16x32_bf16(pa, bv0, acc[qg][0], 0, 0, 0);
                acc[qg][1] = __builtin_amdgcn_mfma_f32_16x16x32_bf16(pa, bv1, acc[qg][1], 0, 0, 0);
            }
        }
    }

    // reduce ls/ts across the 16 lanes (key dim) of each quad group
    #pragma unroll
    for (int m = 1; m < 16; m <<= 1)
        #pragma unroll
        for (int qg = 0; qg < 2; ++qg)
            #pragma unroll
            for (int r = 0; r < 4; ++r) {
                ls[qg][r] += __shfl_xor(ls[qg][r], m);
                ts[qg][r] += __shfl_xor(ts[qg][r], m);
            }

    const int bb = bh >> 2, h = bh & 3;
    float e = 0.f;
    #pragma unroll
    for (int qg = 0; qg < 2; ++qg)
        #pragma unroll
        for (int r = 0; r < 4; ++r) {
            const int q = qb + qg * 16 + quad * 4 + r;
            const float L = ls[qg][r];
            const float invl = 1.f / L;
            short* ap = attT + ((size_t)bb * HW + q) * HID + h * 32;
            ap[n16]      = f2bf(acc[qg][0][r] * invl);
            ap[n16 + 16] = f2bf(acc[qg][1][r] * invl);
            e += (LN2 * ts[qg][r]) * invl - __logf(L);
        }
    e = (n16 == 0) ? e : 0.f;
    e += __shfl_xor(e, 16);
    e += __shfl_xor(e, 32);
    if (lane == 0) atomicAdd(E, e);
}

// ---------------------------------------------------------------------------
extern "C" void kernel_launch(void* const* d_in, const int* in_sizes, int n_in,
                              void* d_out, int out_size, void* d_ws, size_t ws_size,
                              hipStream_t stream) {
    const float* x     = (const float*)d_in[0];
    const float* w_qkv = (const float*)d_in[1];
    const float* b_qkv = (const float*)d_in[2];
    const float* w_out = (const float*)d_in[3];
    const float* b_out = (const float*)d_in[4];
    float* out = (float*)d_out;

    float* wsf    = (float*)d_ws;
    float* E      = wsf;                               // [0] energy accumulator
    int*   ticket = (int*)d_ws + 1;                    // [1] conv2 ticket
    short* Xt   = (short*)(wsf + 16);                  // bf16 [b][s][c]
    short* Wq   = Xt + (size_t)NB * HW * NC;           // bf16 [384][256]
    short* Wo   = Wq + 384 * 256;                      // bf16 [256][128]
    short* Qb   = Wo + 256 * 128;                      // bf16 [bh][s][dh] (xSCALE*log2e)
    short* Kb   = Qb + (size_t)NB * NH * HW * DH;      // bf16 [bh][s'][dh], pair-permuted
    short* Vb   = Kb + (size_t)NB * NH * HW * DH;      // bf16 [bh][dh][s]
    short* attT = Vb + (size_t)NB * NH * HW * DH;      // bf16 [b][s][hid]

    prep<<<dim3(HW / 32, NC / 32, NB + 1), 256, 0, stream>>>(
        x, w_qkv, w_out, Xt, Wq, Wo, wsf);
    conv_mfma<NC, true><<<dim3(18, 6, NB), 256, 0, stream>>>(
        Wq, Xt, b_qkv, nullptr, Qb, Kb, Vb, E, nullptr, 0, nullptr);
    flash7<<<dim3(HW / 128, NB * NH), 256, 0, stream>>>(
        Qb, Kb, Vb, attT, E);
    conv_mfma<HID, false><<<dim3(18, 4, NB), 256, 0, stream>>>(
        Wo, attT, b_out, out, nullptr, nullptr, nullptr, E,
        ticket, 18 * 4 * NB, out + (size_t)NB * NC * HW);
}